// Round 8
// baseline (1217.919 us; speedup 1.0000x reference)
//
#include <hip/hip_runtime.h>

#define NB 4096
#define NT 256

typedef float f32x2 __attribute__((ext_vector_type(2)));

// One wave = ONE chain (4096 waves = 4/SIMD). Lane h owns hidden unit h.
//
// r2-r7 unified theory: gfx950's unified VGPR/AGPR file makes {64 arch +
// 64 AGPR} occupancy-equal to {128 arch}, so the allocator homes the W2
// array in AGPRs and pays v_accvgpr_read per use (~2.6x VALU bloat, VGPR
// counter stuck at 64). Fix: layer2 consumes w2p through inline-asm
// v_pk_fma_f32 with "v" constraints — AGPR is not in the "v" class, so
// all 32 weight pairs must be ARCH-resident at each of the 4 rhs evals
// per step; the RA's copy-cost model must now keep them in arch VGPRs.
// waves_per_eu(4,4): budget 128 arch = exactly 4 waves/SIMD.
//
// h1 broadcast via LDS uniform-address f32x2 reads (broadcast,
// conflict-free, natural even-aligned register pairs for the asm).
// Layer3 reduction: 3 interleaved DPP butterflies (VALU pipe) + readlane.

template <int ctrl, int rm, int bm>
__device__ __forceinline__ float dpp_add(float v) {
    int m = __builtin_amdgcn_update_dpp(0, __builtin_bit_cast(int, v),
                                        ctrl, rm, bm, true);
    return v + __builtin_bit_cast(float, m);
}

__device__ __forceinline__ float rl63(float v) {
    return __builtin_bit_cast(float,
        __builtin_amdgcn_readlane(__builtin_bit_cast(int, v), 63));
}

__global__ __attribute__((amdgpu_flat_work_group_size(256, 256),
                          amdgpu_waves_per_eu(4, 4)))
void tworeac_kernel(
    const float* __restrict__ u, const float* __restrict__ yseq,
    const float* __restrict__ useq, const float* __restrict__ W1,
    const float* __restrict__ b1, const float* __restrict__ W2,
    const float* __restrict__ b2, const float* __restrict__ W3,
    const float* __restrict__ b3, float* __restrict__ out)
{
    const int lane = threadIdx.x & 63;
    const int wave = threadIdx.x >> 6;
    const int b = blockIdx.x * 4 + wave;

    __shared__ float h1s[4][64];

    // ---- weights into registers (lane owns hidden column h = lane) ----
    f32x2 w2p[32];   // {W2[2m][lane], W2[2m+1][lane]} — j-pair per pk_fma
    #pragma unroll
    for (int m = 0; m < 32; ++m)
        w2p[m] = (f32x2){W2[(2 * m) * 64 + lane], W2[(2 * m + 1) * 64 + lane]};
    float w1x[3], w1y[9], w1u[3], w3r[3];
    #pragma unroll
    for (int i = 0; i < 3; ++i) w1x[i] = W1[i * 64 + lane];
    #pragma unroll
    for (int i = 0; i < 9; ++i) w1y[i] = W1[(3 + i) * 64 + lane];
    #pragma unroll
    for (int i = 0; i < 3; ++i) w1u[i] = W1[(12 + i) * 64 + lane];
    #pragma unroll
    for (int k = 0; k < 3; ++k) w3r[k] = W3[lane * 3 + k];
    const float b1h = b1[lane];
    const float b2h = b2[lane];
    const float b30 = b3[0], b31 = b3[1], b32 = b3[2];

    const float* ub  = u    + (size_t)b * NT;
    const float* ysb = yseq + (size_t)b * NT * 9;
    const float* usb = useq + (size_t)b * NT * 3;
    float*       ob  = out  + (size_t)b * NT * 3;

    float x0 = 0.f, x1 = 0.f, x2 = 0.f;
    float base1 = 0.f, ut = 0.f;

    auto rhs = [&](float xa, float xd, float xc,
                   float& d0, float& d1, float& d2) {
        // layer1 (scalar; only x-part varies per RK stage)
        float h1 = fmaf(xa, w1x[0], fmaf(xd, w1x[1], fmaf(xc, w1x[2], base1)));
        h1 = fmaxf(h1, 0.f);
        h1s[wave][lane] = h1;
        __builtin_amdgcn_wave_barrier();
        // layer2: 32 v_pk_fma_f32 over j-pairs via inline asm — "v"
        // constraints force w2p pairs into ARCH VGPRs (not AGPRs).
        f32x2 a0 = (f32x2)0.f, a1 = (f32x2)0.f;
        f32x2 a2 = (f32x2)0.f, a3 = (f32x2)0.f;
        const f32x2* hp = reinterpret_cast<const f32x2*>(&h1s[wave][0]);
        #pragma unroll
        for (int p = 0; p < 4; ++p) {
            f32x2 h0 = hp[8 * p + 0], h1p = hp[8 * p + 1];
            f32x2 h2p = hp[8 * p + 2], h3 = hp[8 * p + 3];
            f32x2 h4 = hp[8 * p + 4], h5 = hp[8 * p + 5];
            f32x2 h6 = hp[8 * p + 6], h7 = hp[8 * p + 7];
            asm("v_pk_fma_f32 %0, %4, %12, %0\n\t"
                "v_pk_fma_f32 %1, %5, %13, %1\n\t"
                "v_pk_fma_f32 %2, %6, %14, %2\n\t"
                "v_pk_fma_f32 %3, %7, %15, %3\n\t"
                "v_pk_fma_f32 %0, %8, %16, %0\n\t"
                "v_pk_fma_f32 %1, %9, %17, %1\n\t"
                "v_pk_fma_f32 %2, %10, %18, %2\n\t"
                "v_pk_fma_f32 %3, %11, %19, %3"
                : "+v"(a0), "+v"(a1), "+v"(a2), "+v"(a3)
                : "v"(h0), "v"(h1p), "v"(h2p), "v"(h3),
                  "v"(h4), "v"(h5), "v"(h6), "v"(h7),
                  "v"(w2p[8 * p + 0]), "v"(w2p[8 * p + 1]),
                  "v"(w2p[8 * p + 2]), "v"(w2p[8 * p + 3]),
                  "v"(w2p[8 * p + 4]), "v"(w2p[8 * p + 5]),
                  "v"(w2p[8 * p + 6]), "v"(w2p[8 * p + 7]));
        }
        __builtin_amdgcn_wave_barrier();
        f32x2 sp = (a0 + a1) + (a2 + a3);
        float h2 = fmaxf(b2h + (sp.x + sp.y), 0.f);
        // layer3 partials; 3 interleaved DPP butterflies
        float q0 = h2 * w3r[0];
        float q1 = h2 * w3r[1];
        float q2 = h2 * w3r[2];
        #define BLVL(CT, RM, BM)                                        \
            q0 = dpp_add<CT, RM, BM>(q0);                               \
            q1 = dpp_add<CT, RM, BM>(q1);                               \
            q2 = dpp_add<CT, RM, BM>(q2);
        BLVL(0x111, 0xf, 0xf)   // row_shr:1
        BLVL(0x112, 0xf, 0xf)   // row_shr:2
        BLVL(0x114, 0xf, 0xe)   // row_shr:4
        BLVL(0x118, 0xf, 0xc)   // row_shr:8
        BLVL(0x142, 0xa, 0xf)   // row_bcast:15
        BLVL(0x143, 0xc, 0xf)   // row_bcast:31
        #undef BLVL
        float s0 = rl63(q0), s1 = rl63(q1), s2 = rl63(q2);
        // _fg (K1=1, BETA=16, F=0.1, VR=1); fast sqrt/rcp (~1 ulp)
        float s = __builtin_amdgcn_sqrtf(fmaf(16.f, xa, 1.f));
        float r = __builtin_amdgcn_rcpf(1.f + s);
        d0 = fmaf(0.1f, ut - xa, -xa) + (s0 + b30);
        d1 = fmaf(0.5f * xa * (s - 1.f), r, -0.1f * xd) + (s1 + b31);
        d2 = fmaf(2.f * xa, r, -0.1f * xc) + (s2 + b32);
    };

    for (int t = 0; t < NT; ++t) {
        // output = state at entry of step t
        if (lane < 3) {
            float v = (lane == 0) ? x0 : (lane == 1 ? x1 : x2);
            ob[t * 3 + lane] = v;
        }

        ut = ub[t];
        base1 = b1h;
        #pragma unroll
        for (int i = 0; i < 9; ++i) base1 = fmaf(ysb[t * 9 + i], w1y[i], base1);
        #pragma unroll
        for (int i = 0; i < 3; ++i) base1 = fmaf(usb[t * 3 + i], w1u[i], base1);

        float k0, k1v, k2v, a0, a1, a2;
        rhs(x0, x1, x2, k0, k1v, k2v);                       // k1
        a0 = k0; a1 = k1v; a2 = k2v;
        rhs(fmaf(0.005f, k0, x0), fmaf(0.005f, k1v, x1),     // k2
            fmaf(0.005f, k2v, x2), k0, k1v, k2v);
        a0 = fmaf(2.f, k0, a0); a1 = fmaf(2.f, k1v, a1); a2 = fmaf(2.f, k2v, a2);
        rhs(fmaf(0.005f, k0, x0), fmaf(0.005f, k1v, x1),     // k3
            fmaf(0.005f, k2v, x2), k0, k1v, k2v);
        a0 = fmaf(2.f, k0, a0); a1 = fmaf(2.f, k1v, a1); a2 = fmaf(2.f, k2v, a2);
        rhs(fmaf(0.01f, k0, x0), fmaf(0.01f, k1v, x1),       // k4
            fmaf(0.01f, k2v, x2), k0, k1v, k2v);
        a0 += k0; a1 += k1v; a2 += k2v;

        const float c = 0.01f / 6.f;
        x0 = fmaf(c, a0, x0);
        x1 = fmaf(c, a1, x1);
        x2 = fmaf(c, a2, x2);
    }
}

extern "C" void kernel_launch(void* const* d_in, const int* in_sizes, int n_in,
                              void* d_out, int out_size, void* d_ws, size_t ws_size,
                              hipStream_t stream) {
    const float* u    = (const float*)d_in[0];
    const float* yseq = (const float*)d_in[1];
    const float* useq = (const float*)d_in[2];
    const float* W1   = (const float*)d_in[3];
    const float* b1   = (const float*)d_in[4];
    const float* W2   = (const float*)d_in[5];
    const float* b2   = (const float*)d_in[6];
    const float* W3   = (const float*)d_in[7];
    const float* b3   = (const float*)d_in[8];
    float* out = (float*)d_out;

    // 4096 chains, 1 per wave, 4 waves/block -> 1024 blocks (4 blocks/CU)
    tworeac_kernel<<<NB / 4, 256, 0, stream>>>(u, yseq, useq, W1, b1, W2, b2,
                                               W3, b3, out);
}

// Round 9
// 1075.565 us; speedup vs baseline: 1.1324x; 1.1324x over previous
//
#include <hip/hip_runtime.h>

#define NB 4096
#define NT 256

typedef float f32x2 __attribute__((ext_vector_type(2)));

// One wave = ONE chain (4096 waves). Lane h owns hidden unit h.
//
// r8 lesson: asm-"v" forcing under waves_per_eu(4,4) (cap 128) made the RA
// SPILL TO SCRATCH (WRITE_SIZE 12.3->26.1 MB) because the live set (~134
// regs: 64 w2 pairs + asm temps + state) exceeds 128. r5 lesson: under
// waves_per_eu(2,4) (cap 256) the RA does allocate >64 arch (84 there).
// This round: asm-"v" pk_fma layer2 (keeps weights out of AGPR) + cap 256
// (removes spill pressure) + once-per-step zero-cost pin (worst case:
// converts per-rhs AGPR copies into per-step copies, a /4 on copy tax).
//
// h1 broadcast via LDS uniform-address f32x2 reads (conflict-free).
// Layer3 reduction: 3 interleaved DPP butterflies (VALU pipe) + readlane.

template <int ctrl, int rm, int bm>
__device__ __forceinline__ float dpp_add(float v) {
    int m = __builtin_amdgcn_update_dpp(0, __builtin_bit_cast(int, v),
                                        ctrl, rm, bm, true);
    return v + __builtin_bit_cast(float, m);
}

__device__ __forceinline__ float rl63(float v) {
    return __builtin_bit_cast(float,
        __builtin_amdgcn_readlane(__builtin_bit_cast(int, v), 63));
}

__global__ __attribute__((amdgpu_flat_work_group_size(256, 256),
                          amdgpu_waves_per_eu(2, 4)))
void tworeac_kernel(
    const float* __restrict__ u, const float* __restrict__ yseq,
    const float* __restrict__ useq, const float* __restrict__ W1,
    const float* __restrict__ b1, const float* __restrict__ W2,
    const float* __restrict__ b2, const float* __restrict__ W3,
    const float* __restrict__ b3, float* __restrict__ out)
{
    const int lane = threadIdx.x & 63;
    const int wave = threadIdx.x >> 6;
    const int b = blockIdx.x * 4 + wave;

    __shared__ float h1s[4][64];

    // ---- weights into registers (lane owns hidden column h = lane) ----
    f32x2 w2p[32];   // {W2[2m][lane], W2[2m+1][lane]} — j-pair per pk_fma
    #pragma unroll
    for (int m = 0; m < 32; ++m)
        w2p[m] = (f32x2){W2[(2 * m) * 64 + lane], W2[(2 * m + 1) * 64 + lane]};
    float w1x[3], w1y[9], w1u[3], w3r[3];
    #pragma unroll
    for (int i = 0; i < 3; ++i) w1x[i] = W1[i * 64 + lane];
    #pragma unroll
    for (int i = 0; i < 9; ++i) w1y[i] = W1[(3 + i) * 64 + lane];
    #pragma unroll
    for (int i = 0; i < 3; ++i) w1u[i] = W1[(12 + i) * 64 + lane];
    #pragma unroll
    for (int k = 0; k < 3; ++k) w3r[k] = W3[lane * 3 + k];
    const float b1h = b1[lane];
    const float b2h = b2[lane];
    const float b30 = b3[0], b31 = b3[1], b32 = b3[2];

    const float* ub  = u    + (size_t)b * NT;
    const float* ysb = yseq + (size_t)b * NT * 9;
    const float* usb = useq + (size_t)b * NT * 3;
    float*       ob  = out  + (size_t)b * NT * 3;

    float x0 = 0.f, x1 = 0.f, x2 = 0.f;
    float base1 = 0.f, ut = 0.f;

    auto rhs = [&](float xa, float xd, float xc,
                   float& d0, float& d1, float& d2) {
        // layer1 (scalar; only x-part varies per RK stage)
        float h1 = fmaf(xa, w1x[0], fmaf(xd, w1x[1], fmaf(xc, w1x[2], base1)));
        h1 = fmaxf(h1, 0.f);
        h1s[wave][lane] = h1;
        __builtin_amdgcn_wave_barrier();
        // layer2: 32 v_pk_fma_f32 over j-pairs via inline asm — "v"
        // constraints keep w2p pairs in ARCH VGPRs (AGPR not in "v" class).
        f32x2 a0 = (f32x2)0.f, a1 = (f32x2)0.f;
        f32x2 a2 = (f32x2)0.f, a3 = (f32x2)0.f;
        const f32x2* hp = reinterpret_cast<const f32x2*>(&h1s[wave][0]);
        #pragma unroll
        for (int p = 0; p < 4; ++p) {
            f32x2 h0 = hp[8 * p + 0], h1p = hp[8 * p + 1];
            f32x2 h2p = hp[8 * p + 2], h3 = hp[8 * p + 3];
            f32x2 h4 = hp[8 * p + 4], h5 = hp[8 * p + 5];
            f32x2 h6 = hp[8 * p + 6], h7 = hp[8 * p + 7];
            asm("v_pk_fma_f32 %0, %4, %12, %0\n\t"
                "v_pk_fma_f32 %1, %5, %13, %1\n\t"
                "v_pk_fma_f32 %2, %6, %14, %2\n\t"
                "v_pk_fma_f32 %3, %7, %15, %3\n\t"
                "v_pk_fma_f32 %0, %8, %16, %0\n\t"
                "v_pk_fma_f32 %1, %9, %17, %1\n\t"
                "v_pk_fma_f32 %2, %10, %18, %2\n\t"
                "v_pk_fma_f32 %3, %11, %19, %3"
                : "+v"(a0), "+v"(a1), "+v"(a2), "+v"(a3)
                : "v"(h0), "v"(h1p), "v"(h2p), "v"(h3),
                  "v"(h4), "v"(h5), "v"(h6), "v"(h7),
                  "v"(w2p[8 * p + 0]), "v"(w2p[8 * p + 1]),
                  "v"(w2p[8 * p + 2]), "v"(w2p[8 * p + 3]),
                  "v"(w2p[8 * p + 4]), "v"(w2p[8 * p + 5]),
                  "v"(w2p[8 * p + 6]), "v"(w2p[8 * p + 7]));
        }
        __builtin_amdgcn_wave_barrier();
        f32x2 sp = (a0 + a1) + (a2 + a3);
        float h2 = fmaxf(b2h + (sp.x + sp.y), 0.f);
        // layer3 partials; 3 interleaved DPP butterflies
        float q0 = h2 * w3r[0];
        float q1 = h2 * w3r[1];
        float q2 = h2 * w3r[2];
        #define BLVL(CT, RM, BM)                                        \
            q0 = dpp_add<CT, RM, BM>(q0);                               \
            q1 = dpp_add<CT, RM, BM>(q1);                               \
            q2 = dpp_add<CT, RM, BM>(q2);
        BLVL(0x111, 0xf, 0xf)   // row_shr:1
        BLVL(0x112, 0xf, 0xf)   // row_shr:2
        BLVL(0x114, 0xf, 0xe)   // row_shr:4
        BLVL(0x118, 0xf, 0xc)   // row_shr:8
        BLVL(0x142, 0xa, 0xf)   // row_bcast:15
        BLVL(0x143, 0xc, 0xf)   // row_bcast:31
        #undef BLVL
        float s0 = rl63(q0), s1 = rl63(q1), s2 = rl63(q2);
        // _fg (K1=1, BETA=16, F=0.1, VR=1); fast sqrt/rcp (~1 ulp)
        float s = __builtin_amdgcn_sqrtf(fmaf(16.f, xa, 1.f));
        float r = __builtin_amdgcn_rcpf(1.f + s);
        d0 = fmaf(0.1f, ut - xa, -xa) + (s0 + b30);
        d1 = fmaf(0.5f * xa * (s - 1.f), r, -0.1f * xd) + (s1 + b31);
        d2 = fmaf(2.f * xa, r, -0.1f * xc) + (s2 + b32);
    };

    for (int t = 0; t < NT; ++t) {
        // Zero-cost arch pin once per step: even if the RA wants AGPR
        // homing, copies become per-step (64) not per-rhs (256).
        #pragma unroll
        for (int m = 0; m < 32; ++m) asm("" : "+v"(w2p[m]));

        // output = state at entry of step t
        if (lane < 3) {
            float v = (lane == 0) ? x0 : (lane == 1 ? x1 : x2);
            ob[t * 3 + lane] = v;
        }

        ut = ub[t];
        base1 = b1h;
        #pragma unroll
        for (int i = 0; i < 9; ++i) base1 = fmaf(ysb[t * 9 + i], w1y[i], base1);
        #pragma unroll
        for (int i = 0; i < 3; ++i) base1 = fmaf(usb[t * 3 + i], w1u[i], base1);

        float k0, k1v, k2v, a0, a1, a2;
        rhs(x0, x1, x2, k0, k1v, k2v);                       // k1
        a0 = k0; a1 = k1v; a2 = k2v;
        rhs(fmaf(0.005f, k0, x0), fmaf(0.005f, k1v, x1),     // k2
            fmaf(0.005f, k2v, x2), k0, k1v, k2v);
        a0 = fmaf(2.f, k0, a0); a1 = fmaf(2.f, k1v, a1); a2 = fmaf(2.f, k2v, a2);
        rhs(fmaf(0.005f, k0, x0), fmaf(0.005f, k1v, x1),     // k3
            fmaf(0.005f, k2v, x2), k0, k1v, k2v);
        a0 = fmaf(2.f, k0, a0); a1 = fmaf(2.f, k1v, a1); a2 = fmaf(2.f, k2v, a2);
        rhs(fmaf(0.01f, k0, x0), fmaf(0.01f, k1v, x1),       // k4
            fmaf(0.01f, k2v, x2), k0, k1v, k2v);
        a0 += k0; a1 += k1v; a2 += k2v;

        const float c = 0.01f / 6.f;
        x0 = fmaf(c, a0, x0);
        x1 = fmaf(c, a1, x1);
        x2 = fmaf(c, a2, x2);
    }
}

extern "C" void kernel_launch(void* const* d_in, const int* in_sizes, int n_in,
                              void* d_out, int out_size, void* d_ws, size_t ws_size,
                              hipStream_t stream) {
    const float* u    = (const float*)d_in[0];
    const float* yseq = (const float*)d_in[1];
    const float* useq = (const float*)d_in[2];
    const float* W1   = (const float*)d_in[3];
    const float* b1   = (const float*)d_in[4];
    const float* W2   = (const float*)d_in[5];
    const float* b2   = (const float*)d_in[6];
    const float* W3   = (const float*)d_in[7];
    const float* b3   = (const float*)d_in[8];
    float* out = (float*)d_out;

    // 4096 chains, 1 per wave, 4 waves/block -> 1024 blocks
    tworeac_kernel<<<NB / 4, 256, 0, stream>>>(u, yseq, useq, W1, b1, W2, b2,
                                               W3, b3, out);
}